// Round 9
// baseline (326.987 us; speedup 1.0000x reference)
//
#include <hip/hip_runtime.h>
#include <cmath>

#define TBL_SIZE (1u << 19)
#define TBL_MASK (TBL_SIZE - 1u)
#define PRIME1 2654435761u
#define PRIME2 805459861u
#define NUM_LEVELS 16
#define QLMAX 7     // quad levels 0..6 (17.6MB); 7+ stays hashed
#define PPB_H 32    // points per 256-thr block, hashed path (8 lanes/point)
#define PPB_Q 128   // points per 256-thr block, quad path  (2 lanes/point)

struct Args {
    float s[NUM_LEVELS];
    uint32_t qoff[QLMAX];  // quad table base per level, in 16B units
    int qrp1[QLMAX];       // R+1 (y/z stride) per quad level
};

typedef float v2f __attribute__((ext_vector_type(2)));

template<int CTRL>
__device__ __forceinline__ float dpp_add(float v) {
    int i = __builtin_bit_cast(int, v);
    int j = __builtin_amdgcn_mov_dpp(i, CTRL, 0xF, 0xF, true);
    return v + __builtin_bit_cast(float, j);
}

__device__ __forceinline__ uint32_t f2bf(float f) {  // f32->bf16 RNE (no NaN in data)
    uint32_t u = __builtin_bit_cast(uint32_t, f);
    return (u + 0x7FFFu + ((u >> 16) & 1u)) >> 16;
}
__device__ __forceinline__ float bflo(uint32_t v) { return __builtin_bit_cast(float, v << 16); }
__device__ __forceinline__ float bfhi(uint32_t v) { return __builtin_bit_cast(float, v & 0xFFFF0000u); }

// Pack hashed levels [QL, QL+NBF) into bf16-pair entries (4B) in ws.
__global__ __launch_bounds__(256) void cvt_hashed_kernel(
    const float* __restrict__ table, uint32_t* __restrict__ dst, int QL, int nentries)
{
    int gid = blockIdx.x * 256 + (int)threadIdx.x;
    if (gid >= nentries) return;
    float2 e = reinterpret_cast<const float2*>(table)[((size_t)QL << 19) + gid];
    dst[gid] = f2bf(e.x) | (f2bf(e.y) << 16);
}

// Quad table for one level: quad[x][y][z] (16B) = bf16 pairs at (y,z),(y,z+1),
// (y+1,z),(y+1,z+1). 2x2 quad tile per thread: 9 gathers / 4 quads.
__global__ __launch_bounds__(256) void build_quads_kernel(
    const float* __restrict__ table, uint4* __restrict__ qt,
    uint32_t qoff, int R, int level, int T, int ntiles)
{
    int id = blockIdx.x * 256 + (int)threadIdx.x;
    if (id >= ntiles) return;
    int t2 = T * T;
    int xp = id / t2; int rem = id - xp * t2;
    int ty = rem / T; int tz = rem - ty * T;
    int y0 = ty * 2, z0 = tz * 2;

    const float2* tb = reinterpret_cast<const float2*>(table) + ((size_t)level << 19);
    uint32_t vals[3][3];
    #pragma unroll
    for (int dy = 0; dy < 3; ++dy)
        #pragma unroll
        for (int dz = 0; dz < 3; ++dz) {
            uint32_t h = (uint32_t)xp ^ ((uint32_t)(y0 + dy) * PRIME1)
                                      ^ ((uint32_t)(z0 + dz) * PRIME2);
            float2 e = tb[h & TBL_MASK];
            vals[dy][dz] = f2bf(e.x) | (f2bf(e.y) << 16);
        }
    int Rp1 = R + 1;
    #pragma unroll
    for (int a = 0; a < 2; ++a)
        #pragma unroll
        for (int c = 0; c < 2; ++c) {
            int Y = y0 + a, Z = z0 + c;
            if (Y <= R && Z <= R) {
                uint4 q;
                q.x = vals[a][c];     q.y = vals[a][c + 1];
                q.z = vals[a + 1][c]; q.w = vals[a + 1][c + 1];
                qt[qoff + ((size_t)xp * Rp1 + Y) * Rp1 + Z] = q;
            }
        }
}

// Main. hashed levels QL..15: corner-per-lane (8 req/pt-level, bf16 if li<NBF);
// quad levels 0..QL-1: plane-per-lane (2x 16B req/pt-level). Hashed contiguous
// per XCD (<=2 levels resident in its L2); quads striped.
__global__ __launch_bounds__(256) void HashEncoding_88837103551034_kernel(
    const float* __restrict__ x,
    const float* __restrict__ table,
    const uint32_t* __restrict__ ws32,
    float* __restrict__ out,
    int npoints, int CH, int CHq, int perXcdHard, int hardTotal, int quadTotal,
    int QL, int NBF, uint32_t bfbase,    // bfbase in 4B units
    Args args)
{
    int b = blockIdx.x; int xcd = b & 7; int sb = b >> 3;
    int t = (int)threadIdx.x;

    if (sb < perXcdHard) {
        // ---- hashed path ----
        int g = xcd * perXcdHard + sb;
        if (g >= hardTotal) return;
        int li = g / CH; int level = QL + li; int chunk = g - li * CH;
        int corner = t & 7;
        int n = chunk * PPB_H + (t >> 3);
        if (n >= npoints) return;

        float x0 = x[(size_t)n * 3 + 0] * 0.5f + 0.5f;
        float x1 = x[(size_t)n * 3 + 1] * 0.5f + 0.5f;
        float x2 = x[(size_t)n * 3 + 2] * 0.5f + 0.5f;
        float sl = args.s[level];
        float sx = x0 * sl, sy = x1 * sl, sz = x2 * sl;
        float fx = floorf(sx), fy = floorf(sy), fz = floorf(sz);
        float ox = sx - fx, oy = sy - fy, oz = sz - fz;
        int bx = (corner >> 2) & 1, by = (corner >> 1) & 1, bz = corner & 1;

        // ceil==floor+1 except integral coords, where the ceil-corner weight is 0.
        uint32_t h = (uint32_t)((int)fx + bx)
                   ^ ((uint32_t)((int)fy + by) * PRIME1)
                   ^ ((uint32_t)((int)fz + bz) * PRIME2);
        uint32_t idx = h & TBL_MASK;

        float f0, f1;
        if (li < NBF) {
            uint32_t v = ws32[bfbase + ((size_t)li << 19) + idx];
            f0 = bflo(v); f1 = bfhi(v);
        } else {
            float2 f = reinterpret_cast<const float2*>(table)[((size_t)level << 19) + idx];
            f0 = f.x; f1 = f.y;
        }
        float w = (bx ? ox : 1.f - ox) * (by ? oy : 1.f - oy) * (bz ? oz : 1.f - oz);
        float e0 = f0 * w, e1 = f1 * w;
        e0 = dpp_add<0xB1>(e0);  e1 = dpp_add<0xB1>(e1);   // xor1
        e0 = dpp_add<0x4E>(e0);  e1 = dpp_add<0x4E>(e1);   // xor2
        e0 = dpp_add<0x141>(e0); e1 = dpp_add<0x141>(e1);  // half-row mirror (0<-7)
        if (corner == 0) {
            v2f res; res.x = e0; res.y = e1;
            __builtin_nontemporal_store(res, (v2f*)(out + (size_t)n * 32 + level * 2));
        }
    } else {
        // ---- quad path ----
        int g = (sb - perXcdHard) * 8 + xcd;
        if (g >= quadTotal) return;
        int li = g / CHq; int level = li; int chunk = g - li * CHq;
        int bx = t & 1;
        int n = chunk * PPB_Q + (t >> 1);
        if (n >= npoints) return;

        float x0 = x[(size_t)n * 3 + 0] * 0.5f + 0.5f;
        float x1 = x[(size_t)n * 3 + 1] * 0.5f + 0.5f;
        float x2 = x[(size_t)n * 3 + 2] * 0.5f + 0.5f;
        float sl = args.s[level];
        float sx = x0 * sl, sy = x1 * sl, sz = x2 * sl;
        float fx = floorf(sx), fy = floorf(sy), fz = floorf(sz);
        float ox = sx - fx, oy = sy - fy, oz = sz - fz;

        int xi = (int)fx + bx, yi = (int)fy, zi = (int)fz;
        int Rp1 = args.qrp1[level];
        const uint4* qt = reinterpret_cast<const uint4*>(ws32);
        uint4 q = qt[args.qoff[level] + ((size_t)xi * Rp1 + yi) * Rp1 + zi];

        float wx = bx ? ox : 1.f - ox;
        float wy0 = 1.f - oy, wy1 = oy, wz0 = 1.f - oz, wz1 = oz;
        float e0 = wx * (wy0 * (wz0 * bflo(q.x) + wz1 * bflo(q.y))
                       + wy1 * (wz0 * bflo(q.z) + wz1 * bflo(q.w)));
        float e1 = wx * (wy0 * (wz0 * bfhi(q.x) + wz1 * bfhi(q.y))
                       + wy1 * (wz0 * bfhi(q.z) + wz1 * bfhi(q.w)));
        e0 = dpp_add<0xB1>(e0);  e1 = dpp_add<0xB1>(e1);   // xor1: sum lane pair
        if (bx == 0) {
            v2f res; res.x = e0; res.y = e1;
            __builtin_nontemporal_store(res, (v2f*)(out + (size_t)n * 32 + level * 2));
        }
    }
}

extern "C" void kernel_launch(void* const* d_in, const int* in_sizes, int n_in,
                              void* d_out, int out_size, void* d_ws, size_t ws_size,
                              hipStream_t stream) {
    const float* x = (const float*)d_in[0];
    const float* table = (const float*)d_in[1];
    float* out = (float*)d_out;
    int npoints = in_sizes[0] / 3;

    Args args;
    double growth = std::exp((std::log(1024.0) - std::log(16.0)) / 15.0);
    for (int l = 0; l < NUM_LEVELS; ++l)
        args.s[l] = (float)std::floor(16.0 * std::pow(growth, (double)l));
    for (int l = 0; l < QLMAX; ++l) { args.qoff[l] = 0; args.qrp1[l] = 1; }

    // Quad-pack levels 0..6 if they fit in ws (17.6MB); all-or-nothing.
    uint64_t cum16 = 0; int QL = 0;
    int Rl[QLMAX], Tl[QLMAX], ntl[QLMAX];
    {
        uint64_t c = 0; bool fits = true;
        for (int l = 0; l < QLMAX; ++l) {
            int R = (int)args.s[l];
            c += (uint64_t)(R + 2) * (R + 1) * (R + 1);
        }
        fits = (c * 16 <= ws_size);
        if (fits) {
            for (int l = 0; l < QLMAX; ++l) {
                int R = (int)args.s[l];
                args.qoff[l] = (uint32_t)cum16; args.qrp1[l] = R + 1;
                Rl[l] = R; Tl[l] = (R + 2) >> 1;
                ntl[l] = (R + 2) * Tl[l] * Tl[l];
                cum16 += (uint64_t)(R + 2) * (R + 1) * (R + 1);
            }
            QL = QLMAX;
        }
    }
    // bf16-pack hashed levels QL..15 into the remainder.
    uint64_t used = cum16 * 16;
    int NBF = 0; uint32_t bfbase = (uint32_t)(used / 4);
    if (ws_size > used) {
        NBF = (int)((ws_size - used) / ((uint64_t)TBL_SIZE * 4));
        if (NBF > NUM_LEVELS - QL) NBF = NUM_LEVELS - QL;
    }

    uint32_t* ws32 = (uint32_t*)d_ws;
    if (NBF > 0) {
        int nent = NBF << 19;
        cvt_hashed_kernel<<<(nent + 255) / 256, 256, 0, stream>>>(
            table, ws32 + bfbase, QL, nent);
    }
    for (int l = 0; l < QL; ++l) {
        build_quads_kernel<<<(ntl[l] + 255) / 256, 256, 0, stream>>>(
            table, (uint4*)d_ws, args.qoff[l], Rl[l], l, Tl[l], ntl[l]);
    }

    int CH  = (npoints + PPB_H - 1) / PPB_H;
    int CHq = (npoints + PPB_Q - 1) / PPB_Q;
    int hardTotal = (NUM_LEVELS - QL) * CH;
    int quadTotal = QL * CHq;
    int perXcdHard = (hardTotal + 7) / 8;
    int perXcdQuad = (quadTotal + 7) / 8;
    int grid = 8 * (perXcdHard + perXcdQuad);

    HashEncoding_88837103551034_kernel<<<grid, 256, 0, stream>>>(
        x, table, ws32, out, npoints, CH, CHq, perXcdHard, hardTotal, quadTotal,
        QL, NBF, bfbase, args);
}

// Round 10
// 294.489 us; speedup vs baseline: 1.1104x; 1.1104x over previous
//
#include <hip/hip_runtime.h>
#include <cmath>

#define TBL_SIZE (1u << 19)
#define TBL_MASK (TBL_SIZE - 1u)
#define PRIME1 2654435761u
#define PRIME2 805459861u
#define NUM_LEVELS 16
#define ZLMAX 7     // z-pair dense levels 0..6 (8.9MB); 7..15 stay hashed bf16
#define PPB_H 32    // points per 256-thr block, hashed path (8 lanes/point)
#define PPB_Z 64    // points per 256-thr block, zpair path  (4 lanes/point)

struct Args {
    float s[NUM_LEVELS];
    uint32_t zoff[ZLMAX];  // zpair table base per level, in 8B units
    int rp2[ZLMAX];        // R+2 (x,y extent)
    int rp1[ZLMAX];        // R+1 (z extent)
};
struct BuildArgs {
    uint32_t woff[ZLMAX + 1];  // cumulative work items per level
    uint32_t zoff[ZLMAX];      // 8B units
    int R[ZLMAX];
};

typedef float v2f __attribute__((ext_vector_type(2)));

template<int CTRL>
__device__ __forceinline__ float dpp_add(float v) {
    int i = __builtin_bit_cast(int, v);
    int j = __builtin_amdgcn_mov_dpp(i, CTRL, 0xF, 0xF, true);
    return v + __builtin_bit_cast(float, j);
}

__device__ __forceinline__ uint32_t f2bf(float f) {  // f32->bf16 RNE (no NaN in data)
    uint32_t u = __builtin_bit_cast(uint32_t, f);
    return (u + 0x7FFFu + ((u >> 16) & 1u)) >> 16;
}
__device__ __forceinline__ float bflo(uint32_t v) { return __builtin_bit_cast(float, v << 16); }
__device__ __forceinline__ float bfhi(uint32_t v) { return __builtin_bit_cast(float, v & 0xFFFF0000u); }

// Pack hashed levels [ZL, ZL+NBF) into bf16-pair entries (4B) in ws.
__global__ __launch_bounds__(256) void cvt_hashed_kernel(
    const float* __restrict__ table, uint32_t* __restrict__ dst, int ZL, int nentries)
{
    int gid = blockIdx.x * 256 + (int)threadIdx.x;
    if (gid >= nentries) return;
    float2 e = reinterpret_cast<const float2*>(table)[((size_t)ZL << 19) + gid];
    dst[gid] = f2bf(e.x) | (f2bf(e.y) << 16);
}

// z-pair dense tables for levels 0..6, one launch. Entry[(x*(R+2)+y)*(R+1)+z]
// (8B) = bf16 pairs at (x,y,z) and (x,y,z+1). Thread = 8-entry z-run: 9 gathers.
__global__ __launch_bounds__(256) void build_zpair_kernel(
    const float* __restrict__ table, uint2* __restrict__ zt, BuildArgs ba)
{
    uint32_t id = blockIdx.x * 256 + threadIdx.x;
    if (id >= ba.woff[ZLMAX]) return;
    int l = 0;
    #pragma unroll
    for (int k = 1; k < ZLMAX; ++k) if (id >= ba.woff[k]) l = k;
    uint32_t rel = id - ba.woff[l];
    int R = ba.R[l];
    int R2 = R + 2;
    int zb = (R + 8) >> 3;                       // ceil((R+1)/8)
    uint32_t span = (uint32_t)(R2 * zb);
    int x = rel / span;
    uint32_t rem = rel - (uint32_t)x * span;
    int y = rem / (uint32_t)zb;
    int z0 = (rem - (uint32_t)y * zb) * 8;

    const float2* tb = reinterpret_cast<const float2*>(table) + ((size_t)l << 19);
    uint32_t hxy = (uint32_t)x ^ ((uint32_t)y * PRIME1);
    uint32_t v[9];
    #pragma unroll
    for (int k = 0; k < 9; ++k) {
        float2 e = tb[(hxy ^ ((uint32_t)(z0 + k) * PRIME2)) & TBL_MASK];
        v[k] = f2bf(e.x) | (f2bf(e.y) << 16);
    }
    uint32_t base = ba.zoff[l] + ((uint32_t)x * R2 + y) * (uint32_t)(R + 1);
    #pragma unroll
    for (int k = 0; k < 8; ++k) {
        int z = z0 + k;
        if (z <= R) zt[base + z] = make_uint2(v[k], v[k + 1]);
    }
}

// Main. hashed levels ZL..15: corner-per-lane (8x 4B req/pt-level);
// zpair levels 0..ZL-1: (bx,by)-per-lane (4x 8B req/pt-level), z-interp in-reg.
__global__ __launch_bounds__(256) void HashEncoding_88837103551034_kernel(
    const float* __restrict__ x,
    const float* __restrict__ table,
    const uint32_t* __restrict__ ws32,
    float* __restrict__ out,
    int npoints, int CH, int CHz, int perXcdHard, int hardTotal, int easyTotal,
    int ZL, int NBF, uint32_t bfbase,    // bfbase in 4B units
    Args args)
{
    int b = blockIdx.x; int xcd = b & 7; int sb = b >> 3;
    int t = (int)threadIdx.x;

    if (sb < perXcdHard) {
        // ---- hashed path ----
        int g = xcd * perXcdHard + sb;
        if (g >= hardTotal) return;
        int li = g / CH; int level = ZL + li; int chunk = g - li * CH;
        int corner = t & 7;
        int n = chunk * PPB_H + (t >> 3);
        if (n >= npoints) return;

        float x0 = x[(size_t)n * 3 + 0] * 0.5f + 0.5f;
        float x1 = x[(size_t)n * 3 + 1] * 0.5f + 0.5f;
        float x2 = x[(size_t)n * 3 + 2] * 0.5f + 0.5f;
        float sl = args.s[level];
        float sx = x0 * sl, sy = x1 * sl, sz = x2 * sl;
        float fx = floorf(sx), fy = floorf(sy), fz = floorf(sz);
        float ox = sx - fx, oy = sy - fy, oz = sz - fz;
        int bx = (corner >> 2) & 1, by = (corner >> 1) & 1, bz = corner & 1;

        // ceil==floor+1 except integral coords, where the ceil-corner weight is 0.
        uint32_t h = (uint32_t)((int)fx + bx)
                   ^ ((uint32_t)((int)fy + by) * PRIME1)
                   ^ ((uint32_t)((int)fz + bz) * PRIME2);
        uint32_t idx = h & TBL_MASK;

        float f0, f1;
        if (li < NBF) {
            uint32_t v = ws32[bfbase + ((size_t)li << 19) + idx];
            f0 = bflo(v); f1 = bfhi(v);
        } else {
            float2 f = reinterpret_cast<const float2*>(table)[((size_t)level << 19) + idx];
            f0 = f.x; f1 = f.y;
        }
        float w = (bx ? ox : 1.f - ox) * (by ? oy : 1.f - oy) * (bz ? oz : 1.f - oz);
        float e0 = f0 * w, e1 = f1 * w;
        e0 = dpp_add<0xB1>(e0);  e1 = dpp_add<0xB1>(e1);   // xor1
        e0 = dpp_add<0x4E>(e0);  e1 = dpp_add<0x4E>(e1);   // xor2
        e0 = dpp_add<0x141>(e0); e1 = dpp_add<0x141>(e1);  // half-row mirror (0<-7)
        if (corner == 0) {
            v2f res; res.x = e0; res.y = e1;
            __builtin_nontemporal_store(res, (v2f*)(out + (size_t)n * 32 + level * 2));
        }
    } else {
        // ---- zpair path ----
        int g = (sb - perXcdHard) * 8 + xcd;
        if (g >= easyTotal) return;
        int level = g / CHz; int chunk = g - level * CHz;
        int lane = t & 3; int bx = lane & 1; int by = (lane >> 1) & 1;
        int n = chunk * PPB_Z + (t >> 2);
        if (n >= npoints) return;

        float x0 = x[(size_t)n * 3 + 0] * 0.5f + 0.5f;
        float x1 = x[(size_t)n * 3 + 1] * 0.5f + 0.5f;
        float x2 = x[(size_t)n * 3 + 2] * 0.5f + 0.5f;
        float sl = args.s[level];
        float sx = x0 * sl, sy = x1 * sl, sz = x2 * sl;
        float fx = floorf(sx), fy = floorf(sy), fz = floorf(sz);
        float ox = sx - fx, oy = sy - fy, oz = sz - fz;

        int xi = (int)fx + bx, yi = (int)fy + by, zi = (int)fz;
        int R2 = args.rp2[level], Z1 = args.rp1[level];
        const uint2* zt = reinterpret_cast<const uint2*>(ws32);
        uint2 e = zt[args.zoff[level] + ((uint32_t)xi * R2 + yi) * (uint32_t)Z1 + zi];

        float wz0 = 1.f - oz, wz1 = oz;
        float g0 = wz0 * bflo(e.x) + wz1 * bflo(e.y);
        float g1 = wz0 * bfhi(e.x) + wz1 * bfhi(e.y);
        float w = (bx ? ox : 1.f - ox) * (by ? oy : 1.f - oy);
        float e0 = g0 * w, e1 = g1 * w;
        e0 = dpp_add<0xB1>(e0); e1 = dpp_add<0xB1>(e1);    // xor1: bx pair
        e0 = dpp_add<0x4E>(e0); e1 = dpp_add<0x4E>(e1);    // xor2: by pair
        if (lane == 0) {
            v2f res; res.x = e0; res.y = e1;
            __builtin_nontemporal_store(res, (v2f*)(out + (size_t)n * 32 + level * 2));
        }
    }
}

extern "C" void kernel_launch(void* const* d_in, const int* in_sizes, int n_in,
                              void* d_out, int out_size, void* d_ws, size_t ws_size,
                              hipStream_t stream) {
    const float* x = (const float*)d_in[0];
    const float* table = (const float*)d_in[1];
    float* out = (float*)d_out;
    int npoints = in_sizes[0] / 3;

    Args args;
    BuildArgs ba;
    double growth = std::exp((std::log(1024.0) - std::log(16.0)) / 15.0);
    for (int l = 0; l < NUM_LEVELS; ++l)
        args.s[l] = (float)std::floor(16.0 * std::pow(growth, (double)l));
    for (int l = 0; l < ZLMAX; ++l) { args.zoff[l] = 0; args.rp2[l] = 1; args.rp1[l] = 1; }

    // Size zpair tables for levels 0..6 (all-or-nothing, ~8.9MB).
    uint64_t cum8 = 0, wcum = 0;
    {
        uint64_t c = 0;
        for (int l = 0; l < ZLMAX; ++l) {
            int R = (int)args.s[l];
            c += (uint64_t)(R + 2) * (R + 2) * (R + 1);
        }
        if (c * 8 <= ws_size) {
            for (int l = 0; l < ZLMAX; ++l) {
                int R = (int)args.s[l];
                args.zoff[l] = (uint32_t)cum8; args.rp2[l] = R + 2; args.rp1[l] = R + 1;
                ba.zoff[l] = (uint32_t)cum8; ba.R[l] = R;
                ba.woff[l] = (uint32_t)wcum;
                int zb = (R + 8) >> 3;
                wcum += (uint64_t)(R + 2) * (R + 2) * zb;
                cum8 += (uint64_t)(R + 2) * (R + 2) * (R + 1);
            }
            ba.woff[ZLMAX] = (uint32_t)wcum;
        }
    }
    int ZL = (cum8 > 0) ? ZLMAX : 0;

    // bf16-pack hashed levels ZL..15 into the remainder.
    uint64_t used = cum8 * 8;
    int NBF = 0; uint32_t bfbase = (uint32_t)(used / 4);
    if (ws_size > used) {
        NBF = (int)((ws_size - used) / ((uint64_t)TBL_SIZE * 4));
        if (NBF > NUM_LEVELS - ZL) NBF = NUM_LEVELS - ZL;
    }

    uint32_t* ws32 = (uint32_t*)d_ws;
    if (NBF > 0) {
        int nent = NBF << 19;
        cvt_hashed_kernel<<<(nent + 255) / 256, 256, 0, stream>>>(
            table, ws32 + bfbase, ZL, nent);
    }
    if (ZL == ZLMAX) {
        build_zpair_kernel<<<((int)wcum + 255) / 256, 256, 0, stream>>>(
            table, (uint2*)d_ws, ba);
    }

    int CH  = (npoints + PPB_H - 1) / PPB_H;
    int CHz = (npoints + PPB_Z - 1) / PPB_Z;
    int hardTotal = (NUM_LEVELS - ZL) * CH;
    int easyTotal = ZL * CHz;
    int perXcdHard = (hardTotal + 7) / 8;
    int perXcdEasy = (easyTotal + 7) / 8;
    int grid = 8 * (perXcdHard + perXcdEasy);

    HashEncoding_88837103551034_kernel<<<grid, 256, 0, stream>>>(
        x, table, ws32, out, npoints, CH, CHz, perXcdHard, hardTotal, easyTotal,
        ZL, NBF, bfbase, args);
}

// Round 11
// 256.402 us; speedup vs baseline: 1.2753x; 1.1485x over previous
//
#include <hip/hip_runtime.h>
#include <cmath>

#define TBL_SIZE (1u << 19)
#define TBL_MASK (TBL_SIZE - 1u)
#define PRIME1 2654435761u
#define PRIME2 805459861u
#define NUM_LEVELS 16
#define PPB 32      // points per 256-thr block, hashed path (8 lanes/point)

// Dense LDS-resident levels 0..2 (resolutions 16,21,27 -> dims s+1)
#define D0g 17
#define D1g 22
#define D2g 28
#define NW0 (D0g*D0g*D0g)        // 4913
#define NW1 (D1g*D1g*D1g)        // 10648
#define NW2 (D2g*D2g*D2g)        // 21952
#define NWTOT (NW0+NW1+NW2)      // 37513 words
#define LDSB (NWTOT*4)           // 150052 B <= 160KB

struct Args { float s[NUM_LEVELS]; };

typedef float v2f __attribute__((ext_vector_type(2)));

template<int CTRL>
__device__ __forceinline__ float dpp_add(float v) {
    int i = __builtin_bit_cast(int, v);
    int j = __builtin_amdgcn_mov_dpp(i, CTRL, 0xF, 0xF, true);
    return v + __builtin_bit_cast(float, j);
}

__device__ __forceinline__ uint32_t f2bf(float f) {  // f32->bf16 RNE (no NaN in data)
    uint32_t u = __builtin_bit_cast(uint32_t, f);
    return (u + 0x7FFFu + ((u >> 16) & 1u)) >> 16;
}
__device__ __forceinline__ float bflo(uint32_t v) { return __builtin_bit_cast(float, v << 16); }
__device__ __forceinline__ float bfhi(uint32_t v) { return __builtin_bit_cast(float, v & 0xFFFF0000u); }

// Pack hashed levels [L0, L0+NBF) into bf16-pair entries (4B) at ws[0..).
__global__ __launch_bounds__(256) void cvt_hashed_kernel(
    const float* __restrict__ table, uint32_t* __restrict__ dst, int L0, int nentries)
{
    int gid = blockIdx.x * 256 + (int)threadIdx.x;
    if (gid >= nentries) return;
    float2 e = reinterpret_cast<const float2*>(table)[((size_t)L0 << 19) + gid];
    dst[gid] = f2bf(e.x) | (f2bf(e.y) << 16);
}

// Dense bf16-pair tables for levels 0..2 (37.5k entries, one tiny launch).
__global__ __launch_bounds__(256) void build_dense3_kernel(
    const float* __restrict__ table, uint32_t* __restrict__ dst)
{
    int id = blockIdx.x * 256 + (int)threadIdx.x;
    if (id >= NWTOT) return;
    int l, rel, D;
    if (id < NW0)            { l = 0; rel = id;             D = D0g; }
    else if (id < NW0 + NW1) { l = 1; rel = id - NW0;       D = D1g; }
    else                     { l = 2; rel = id - NW0 - NW1; D = D2g; }
    int d2 = D * D;
    int xp = rel / d2; int rem = rel - xp * d2;
    int yp = rem / D;  int zp = rem - yp * D;
    uint32_t h = (uint32_t)xp ^ ((uint32_t)yp * PRIME1) ^ ((uint32_t)zp * PRIME2);
    float2 e = reinterpret_cast<const float2*>(table)[((size_t)l << 19) + (h & TBL_MASK)];
    dst[id] = f2bf(e.x) | (f2bf(e.y) << 16);
}

// Levels 0..2 served from LDS (divergent reads hit the 32-bank LDS pipe, not
// the TCP request-rate floor). One block/CU (150KB dyn LDS), grid-stride.
__global__ __launch_bounds__(1024) void lds_levels_kernel(
    const float* __restrict__ x, const uint32_t* __restrict__ wsdense,
    float* __restrict__ out, int npoints, int nchunks,
    float s0, float s1, float s2)
{
    extern __shared__ uint32_t lds[];
    for (int i = (int)threadIdx.x; i < NWTOT; i += 1024) lds[i] = wsdense[i];
    __syncthreads();

    const int t = (int)threadIdx.x;
    const int corner = t & 7, p = t >> 3;          // 128 points per pass
    const int bx = (corner >> 2) & 1, by = (corner >> 1) & 1, bz = corner & 1;

    for (int c = (int)blockIdx.x; c < nchunks; c += (int)gridDim.x) {
        int n = c * 128 + p;
        if (n < npoints) {
            float x0 = x[(size_t)n * 3 + 0] * 0.5f + 0.5f;
            float x1 = x[(size_t)n * 3 + 1] * 0.5f + 0.5f;
            float x2 = x[(size_t)n * 3 + 2] * 0.5f + 0.5f;
            const float ss[3] = {s0, s1, s2};
            const int   dd[3] = {D0g, D1g, D2g};
            const int   bb[3] = {0, NW0, NW0 + NW1};
            #pragma unroll
            for (int l = 0; l < 3; ++l) {
                float sx = x0 * ss[l], sy = x1 * ss[l], sz = x2 * ss[l];
                float fx = floorf(sx), fy = floorf(sy), fz = floorf(sz);
                float ox = sx - fx, oy = sy - fy, oz = sz - fz;
                int D = dd[l];
                int idx = (((int)fx + bx) * D + (int)fy + by) * D + (int)fz + bz;
                int mx = D * D * D - 1;
                idx = idx < mx ? idx : mx;   // x01==1.0 phantom: weight 0; stay in-bounds
                uint32_t v = lds[bb[l] + idx];
                float w = (bx ? ox : 1.f - ox) * (by ? oy : 1.f - oy) * (bz ? oz : 1.f - oz);
                float e0 = bflo(v) * w, e1 = bfhi(v) * w;
                e0 = dpp_add<0xB1>(e0);  e1 = dpp_add<0xB1>(e1);   // xor1
                e0 = dpp_add<0x4E>(e0);  e1 = dpp_add<0x4E>(e1);   // xor2
                e0 = dpp_add<0x141>(e0); e1 = dpp_add<0x141>(e1);  // half-row mirror
                if (corner == 0) {
                    v2f r; r.x = e0; r.y = e1;
                    __builtin_nontemporal_store(r, (v2f*)(out + (size_t)n * 32 + l * 2));
                }
            }
        }
    }
}

// Hashed levels [L0,16): corner-per-lane, bf16 (li<NBF) else f32. XCD-affine
// contiguous split (balanced by construction: all levels equal request cost).
__global__ __launch_bounds__(256) void HashEncoding_88837103551034_kernel(
    const float* __restrict__ x,
    const float* __restrict__ table,
    const uint32_t* __restrict__ bfws,
    float* __restrict__ out,
    int npoints, int CH, int perXcd, int total, int L0, int NBF,
    Args args)
{
    int b = blockIdx.x; int xcd = b & 7; int sb = b >> 3;
    int g = xcd * perXcd + sb;
    if (g >= total) return;
    int li = g / CH; int level = L0 + li; int chunk = g - li * CH;
    int t = (int)threadIdx.x;
    int corner = t & 7;
    int n = chunk * PPB + (t >> 3);
    if (n >= npoints) return;

    float x0 = x[(size_t)n * 3 + 0] * 0.5f + 0.5f;
    float x1 = x[(size_t)n * 3 + 1] * 0.5f + 0.5f;
    float x2 = x[(size_t)n * 3 + 2] * 0.5f + 0.5f;
    float sl = args.s[level];
    float sx = x0 * sl, sy = x1 * sl, sz = x2 * sl;
    float fx = floorf(sx), fy = floorf(sy), fz = floorf(sz);
    float ox = sx - fx, oy = sy - fy, oz = sz - fz;
    int bx = (corner >> 2) & 1, by = (corner >> 1) & 1, bz = corner & 1;

    // ceil==floor+1 except integral coords, where the ceil-corner weight is 0.
    uint32_t h = (uint32_t)((int)fx + bx)
               ^ ((uint32_t)((int)fy + by) * PRIME1)
               ^ ((uint32_t)((int)fz + bz) * PRIME2);
    uint32_t idx = h & TBL_MASK;

    float f0, f1;
    if (li < NBF) {
        uint32_t v = bfws[((size_t)li << 19) + idx];
        f0 = bflo(v); f1 = bfhi(v);
    } else {
        float2 f = reinterpret_cast<const float2*>(table)[((size_t)level << 19) + idx];
        f0 = f.x; f1 = f.y;
    }
    float w = (bx ? ox : 1.f - ox) * (by ? oy : 1.f - oy) * (bz ? oz : 1.f - oz);
    float e0 = f0 * w, e1 = f1 * w;
    e0 = dpp_add<0xB1>(e0);  e1 = dpp_add<0xB1>(e1);   // xor1
    e0 = dpp_add<0x4E>(e0);  e1 = dpp_add<0x4E>(e1);   // xor2
    e0 = dpp_add<0x141>(e0); e1 = dpp_add<0x141>(e1);  // half-row mirror (0<-7)
    if (corner == 0) {
        v2f res; res.x = e0; res.y = e1;
        __builtin_nontemporal_store(res, (v2f*)(out + (size_t)n * 32 + level * 2));
    }
}

extern "C" void kernel_launch(void* const* d_in, const int* in_sizes, int n_in,
                              void* d_out, int out_size, void* d_ws, size_t ws_size,
                              hipStream_t stream) {
    const float* x = (const float*)d_in[0];
    const float* table = (const float*)d_in[1];
    float* out = (float*)d_out;
    int npoints = in_sizes[0] / 3;

    Args args;
    double growth = std::exp((std::log(1024.0) - std::log(16.0)) / 15.0);
    for (int l = 0; l < NUM_LEVELS; ++l)
        args.s[l] = (float)std::floor(16.0 * std::pow(growth, (double)l));

    int CH = (npoints + PPB - 1) / PPB;
    uint32_t* ws32 = (uint32_t*)d_ws;

    bool dimsOk = ((int)args.s[0] == 16) && ((int)args.s[1] == 21) && ((int)args.s[2] == 27);
    size_t needA = ((size_t)13 * TBL_SIZE + (size_t)NWTOT) * 4;   // ~27.4MB

    if (dimsOk && ws_size >= needA) {
        // Plan A: LDS levels 0-2, bf16-hashed levels 3-15.
        int nent = 13 << 19;
        cvt_hashed_kernel<<<nent / 256, 256, 0, stream>>>(table, ws32, 3, nent);
        uint32_t* wsdense = ws32 + (size_t)13 * TBL_SIZE;
        build_dense3_kernel<<<(NWTOT + 255) / 256, 256, 0, stream>>>(table, wsdense);

        hipFuncSetAttribute(reinterpret_cast<const void*>(lds_levels_kernel),
                            hipFuncAttributeMaxDynamicSharedMemorySize, LDSB);
        int nchunks = (npoints + 127) / 128;
        lds_levels_kernel<<<256, 1024, LDSB, stream>>>(
            x, wsdense, out, npoints, nchunks, args.s[0], args.s[1], args.s[2]);

        int total = 13 * CH;
        int perXcd = (total + 7) / 8;
        HashEncoding_88837103551034_kernel<<<8 * perXcd, 256, 0, stream>>>(
            x, table, ws32, out, npoints, CH, perXcd, total, 3, 13, args);
    } else {
        // Plan C: all 16 levels hashed from f32 table (proven fallback).
        int total = 16 * CH;
        int perXcd = (total + 7) / 8;
        HashEncoding_88837103551034_kernel<<<8 * perXcd, 256, 0, stream>>>(
            x, table, ws32, out, npoints, CH, perXcd, total, 0, 0, args);
    }
}

// Round 12
// 251.595 us; speedup vs baseline: 1.2997x; 1.0191x over previous
//
#include <hip/hip_runtime.h>
#include <cmath>

#define TBL_SIZE (1u << 19)
#define TBL_MASK (TBL_SIZE - 1u)
#define PRIME1 2654435761u
#define PRIME2 805459861u
#define NUM_LEVELS 16
#define PPB 32      // points per 256-thr block, hashed path (8 lanes/point)

// Dense LDS-resident levels 0..2 (resolutions 16,21,27 -> dims s+1)
#define D0g 17
#define D1g 22
#define D2g 28
#define NW0 (D0g*D0g*D0g)        // 4913
#define NW1 (D1g*D1g*D1g)        // 10648
#define NW2 (D2g*D2g*D2g)        // 21952
#define NWTOT (NW0+NW1+NW2)      // 37513 words in ws (unpadded)
// LDS layout with per-level pad = max static corner offset (D*D+D+1), zeroed.
#define PAD0 (D0g*D0g+D0g+1)     // 307
#define PAD1 (D1g*D1g+D1g+1)     // 507
#define PAD2 (D2g*D2g+D2g+1)     // 813
#define LB0  0
#define LB1  (LB0+NW0+PAD0)
#define LB2  (LB1+NW1+PAD1)
#define LTOT (LB2+NW2+PAD2)      // 39140 words = 156560 B <= 160KB
#define LDSB (LTOT*4)

struct Args { float s[NUM_LEVELS]; };

typedef float v2f __attribute__((ext_vector_type(2)));
typedef float v4f __attribute__((ext_vector_type(4)));

template<int CTRL>
__device__ __forceinline__ float dpp_add(float v) {
    int i = __builtin_bit_cast(int, v);
    int j = __builtin_amdgcn_mov_dpp(i, CTRL, 0xF, 0xF, true);
    return v + __builtin_bit_cast(float, j);
}

__device__ __forceinline__ uint32_t f2bf(float f) {  // f32->bf16 RNE (no NaN in data)
    uint32_t u = __builtin_bit_cast(uint32_t, f);
    return (u + 0x7FFFu + ((u >> 16) & 1u)) >> 16;
}
__device__ __forceinline__ float bflo(uint32_t v) { return __builtin_bit_cast(float, v << 16); }
__device__ __forceinline__ float bfhi(uint32_t v) { return __builtin_bit_cast(float, v & 0xFFFF0000u); }

// One launch: dense tables for levels 0..2 (first NWTOT ids) + bf16-pack levels
// 3..15 (remaining ids) into ws.
__global__ __launch_bounds__(256) void prep_kernel(
    const float* __restrict__ table, uint32_t* __restrict__ bfws,
    uint32_t* __restrict__ densews, int ncvt)
{
    int gid = blockIdx.x * 256 + (int)threadIdx.x;
    if (gid < NWTOT) {
        int l, rel, D;
        if (gid < NW0)            { l = 0; rel = gid;             D = D0g; }
        else if (gid < NW0 + NW1) { l = 1; rel = gid - NW0;       D = D1g; }
        else                      { l = 2; rel = gid - NW0 - NW1; D = D2g; }
        int d2 = D * D;
        int xp = rel / d2; int rem = rel - xp * d2;
        int yp = rem / D;  int zp = rem - yp * D;
        uint32_t h = (uint32_t)xp ^ ((uint32_t)yp * PRIME1) ^ ((uint32_t)zp * PRIME2);
        float2 e = reinterpret_cast<const float2*>(table)[((size_t)l << 19) + (h & TBL_MASK)];
        densews[gid] = f2bf(e.x) | (f2bf(e.y) << 16);
    } else {
        int rel = gid - NWTOT;
        if (rel >= ncvt) return;
        float2 e = reinterpret_cast<const float2*>(table)[((size_t)3 << 19) + rel];
        bfws[rel] = f2bf(e.x) | (f2bf(e.y) << 16);
    }
}

// Levels 0..2 from LDS, POINT-per-thread: 24 ds_read_b32 with static offsets,
// no dpp, one float4+float2 store per point (levels 0..2 are contiguous in out).
__global__ __launch_bounds__(1024) void lds_levels_kernel(
    const float* __restrict__ x, const uint32_t* __restrict__ densews,
    float* __restrict__ out, int npoints,
    float s0, float s1, float s2)
{
    extern __shared__ uint32_t lds[];
    // zero (covers pads), sync, stage tables
    for (int i = (int)threadIdx.x; i < LTOT; i += 1024) lds[i] = 0;
    __syncthreads();
    for (int i = (int)threadIdx.x; i < NW0; i += 1024) lds[LB0 + i] = densews[i];
    for (int i = (int)threadIdx.x; i < NW1; i += 1024) lds[LB1 + i] = densews[NW0 + i];
    for (int i = (int)threadIdx.x; i < NW2; i += 1024) lds[LB2 + i] = densews[NW0 + NW1 + i];
    __syncthreads();

    float acc[6];
    for (int n = blockIdx.x * 1024 + (int)threadIdx.x; n < npoints; n += (int)gridDim.x * 1024) {
        float x0 = x[(size_t)n * 3 + 0] * 0.5f + 0.5f;
        float x1 = x[(size_t)n * 3 + 1] * 0.5f + 0.5f;
        float x2 = x[(size_t)n * 3 + 2] * 0.5f + 0.5f;

#define DO_LEVEL(LI, DCONST, LBASE, SCALE)                                        \
        {                                                                         \
            const int D = DCONST, D2 = DCONST * DCONST;                           \
            float sx = x0 * SCALE, sy = x1 * SCALE, sz = x2 * SCALE;              \
            float fx = floorf(sx), fy = floorf(sy), fz = floorf(sz);              \
            float ox = sx - fx, oy = sy - fy, oz = sz - fz;                       \
            int base = LBASE + ((int)fx * D + (int)fy) * D + (int)fz;             \
            uint32_t v000 = lds[base];            uint32_t v001 = lds[base + 1];  \
            uint32_t v010 = lds[base + D];        uint32_t v011 = lds[base + D + 1]; \
            uint32_t v100 = lds[base + D2];       uint32_t v101 = lds[base + D2 + 1]; \
            uint32_t v110 = lds[base + D2 + D];   uint32_t v111 = lds[base + D2 + D + 1]; \
            float gx0 = 1.f - ox, gy0 = 1.f - oy, gz0 = 1.f - oz;                 \
            float w000 = gx0 * gy0 * gz0, w001 = gx0 * gy0 * oz;                  \
            float w010 = gx0 * oy * gz0,  w011 = gx0 * oy * oz;                   \
            float w100 = ox * gy0 * gz0,  w101 = ox * gy0 * oz;                   \
            float w110 = ox * oy * gz0,   w111 = ox * oy * oz;                    \
            acc[LI*2+0] = bflo(v000)*w000 + bflo(v001)*w001 + bflo(v010)*w010     \
                        + bflo(v011)*w011 + bflo(v100)*w100 + bflo(v101)*w101     \
                        + bflo(v110)*w110 + bflo(v111)*w111;                      \
            acc[LI*2+1] = bfhi(v000)*w000 + bfhi(v001)*w001 + bfhi(v010)*w010     \
                        + bfhi(v011)*w011 + bfhi(v100)*w100 + bfhi(v101)*w101     \
                        + bfhi(v110)*w110 + bfhi(v111)*w111;                      \
        }
        DO_LEVEL(0, D0g, LB0, s0)
        DO_LEVEL(1, D1g, LB1, s1)
        DO_LEVEL(2, D2g, LB2, s2)
#undef DO_LEVEL

        v4f a; a.x = acc[0]; a.y = acc[1]; a.z = acc[2]; a.w = acc[3];
        v2f b; b.x = acc[4]; b.y = acc[5];
        float* o = out + (size_t)n * 32;
        __builtin_nontemporal_store(a, (v4f*)o);
        __builtin_nontemporal_store(b, (v2f*)(o + 4));
    }
}

// Hashed levels [L0,16): corner-per-lane, bf16 (li<NBF) else f32. XCD-affine
// contiguous split. (Proven 194us at the TCP request floor -- unchanged.)
__global__ __launch_bounds__(256) void HashEncoding_88837103551034_kernel(
    const float* __restrict__ x,
    const float* __restrict__ table,
    const uint32_t* __restrict__ bfws,
    float* __restrict__ out,
    int npoints, int CH, int perXcd, int total, int L0, int NBF,
    Args args)
{
    int b = blockIdx.x; int xcd = b & 7; int sb = b >> 3;
    int g = xcd * perXcd + sb;
    if (g >= total) return;
    int li = g / CH; int level = L0 + li; int chunk = g - li * CH;
    int t = (int)threadIdx.x;
    int corner = t & 7;
    int n = chunk * PPB + (t >> 3);
    if (n >= npoints) return;

    float x0 = x[(size_t)n * 3 + 0] * 0.5f + 0.5f;
    float x1 = x[(size_t)n * 3 + 1] * 0.5f + 0.5f;
    float x2 = x[(size_t)n * 3 + 2] * 0.5f + 0.5f;
    float sl = args.s[level];
    float sx = x0 * sl, sy = x1 * sl, sz = x2 * sl;
    float fx = floorf(sx), fy = floorf(sy), fz = floorf(sz);
    float ox = sx - fx, oy = sy - fy, oz = sz - fz;
    int bx = (corner >> 2) & 1, by = (corner >> 1) & 1, bz = corner & 1;

    // ceil==floor+1 except integral coords, where the ceil-corner weight is 0.
    uint32_t h = (uint32_t)((int)fx + bx)
               ^ ((uint32_t)((int)fy + by) * PRIME1)
               ^ ((uint32_t)((int)fz + bz) * PRIME2);
    uint32_t idx = h & TBL_MASK;

    float f0, f1;
    if (li < NBF) {
        uint32_t v = bfws[((size_t)li << 19) + idx];
        f0 = bflo(v); f1 = bfhi(v);
    } else {
        float2 f = reinterpret_cast<const float2*>(table)[((size_t)level << 19) + idx];
        f0 = f.x; f1 = f.y;
    }
    float w = (bx ? ox : 1.f - ox) * (by ? oy : 1.f - oy) * (bz ? oz : 1.f - oz);
    float e0 = f0 * w, e1 = f1 * w;
    e0 = dpp_add<0xB1>(e0);  e1 = dpp_add<0xB1>(e1);   // xor1
    e0 = dpp_add<0x4E>(e0);  e1 = dpp_add<0x4E>(e1);   // xor2
    e0 = dpp_add<0x141>(e0); e1 = dpp_add<0x141>(e1);  // half-row mirror (0<-7)
    if (corner == 0) {
        v2f res; res.x = e0; res.y = e1;
        __builtin_nontemporal_store(res, (v2f*)(out + (size_t)n * 32 + level * 2));
    }
}

extern "C" void kernel_launch(void* const* d_in, const int* in_sizes, int n_in,
                              void* d_out, int out_size, void* d_ws, size_t ws_size,
                              hipStream_t stream) {
    const float* x = (const float*)d_in[0];
    const float* table = (const float*)d_in[1];
    float* out = (float*)d_out;
    int npoints = in_sizes[0] / 3;

    Args args;
    double growth = std::exp((std::log(1024.0) - std::log(16.0)) / 15.0);
    for (int l = 0; l < NUM_LEVELS; ++l)
        args.s[l] = (float)std::floor(16.0 * std::pow(growth, (double)l));

    int CH = (npoints + PPB - 1) / PPB;
    uint32_t* ws32 = (uint32_t*)d_ws;

    bool dimsOk = ((int)args.s[0] == 16) && ((int)args.s[1] == 21) && ((int)args.s[2] == 27);
    size_t needA = ((size_t)13 * TBL_SIZE + (size_t)NWTOT) * 4;   // ~27.4MB

    if (dimsOk && ws_size >= needA) {
        // Plan A: LDS levels 0-2 (point-per-thread), bf16-hashed levels 3-15.
        uint32_t* wsdense = ws32 + (size_t)13 * TBL_SIZE;
        int ncvt = 13 << 19;
        int ptot = NWTOT + ncvt;
        prep_kernel<<<(ptot + 255) / 256, 256, 0, stream>>>(table, ws32, wsdense, ncvt);

        hipFuncSetAttribute(reinterpret_cast<const void*>(lds_levels_kernel),
                            hipFuncAttributeMaxDynamicSharedMemorySize, LDSB);
        lds_levels_kernel<<<256, 1024, LDSB, stream>>>(
            x, wsdense, out, npoints, args.s[0], args.s[1], args.s[2]);

        int total = 13 * CH;
        int perXcd = (total + 7) / 8;
        HashEncoding_88837103551034_kernel<<<8 * perXcd, 256, 0, stream>>>(
            x, table, ws32, out, npoints, CH, perXcd, total, 3, 13, args);
    } else {
        // Plan C: all 16 levels hashed from f32 table (proven fallback).
        int total = 16 * CH;
        int perXcd = (total + 7) / 8;
        HashEncoding_88837103551034_kernel<<<8 * perXcd, 256, 0, stream>>>(
            x, table, ws32, out, npoints, CH, perXcd, total, 0, 0, args);
    }
}